// Round 1
// 222.458 us; speedup vs baseline: 1.0039x; 1.0039x over previous
//
#include <hip/hip_runtime.h>
#include <hip/hip_bf16.h>

#define BATCH 4
#define SEQ   2048
#define DIN   1024
#define DOUT  1024
#define N3    3072
#define MTOT  (BATCH*SEQ)

typedef __hip_bfloat16 bf16;
typedef __attribute__((ext_vector_type(8))) short bf16x8;
typedef __attribute__((ext_vector_type(4))) float f32x4;

#define MFMA(a,b,c) __builtin_amdgcn_mfma_f32_16x16x32_bf16(a,b,c,0,0,0)

union pack4 { bf16 h[4]; uint2 u2; };
union pack8 { bf16 h[8]; bf16x8 v; };

// async 16B global->LDS (DMA, no VGPR round-trip)
__device__ __forceinline__ void gl16(const bf16* g, bf16* l)
{
    __builtin_amdgcn_global_load_lds(
        (const __attribute__((address_space(1))) void*)g,
        (__attribute__((address_space(3))) void*)l, 16, 0, 0);
}

// ---------------- fused conversions (unchanged) ----------------

__global__ __launch_bounds__(256)
void k_prep(const float* __restrict__ x, const float* __restrict__ Wq,
            const float* __restrict__ Wk, const float* __restrict__ Wv,
            bf16* __restrict__ xb, bf16* __restrict__ Wt)
{
    __shared__ bf16 t[64][68];
    const int bid = blockIdx.x;
    if (bid < 8192) {
        long i = ((long)bid * 256 + threadIdx.x) * 4;
        float4 v = *(const float4*)(x + i);
        pack4 o;
        o.h[0] = __float2bfloat16(v.x);
        o.h[1] = __float2bfloat16(v.y);
        o.h[2] = __float2bfloat16(v.z);
        o.h[3] = __float2bfloat16(v.w);
        *(uint2*)(xb + i) = o.u2;
        return;
    }
    const int idx = bid - 8192;                // 0..767
    const int mat = idx >> 8;
    const int rem = idx & 255;
    const int k0 = (rem >> 4) * 64, n0 = (rem & 15) * 64;
    const float* W = (mat == 0) ? Wq : ((mat == 1) ? Wk : Wv);
#pragma unroll
    for (int p = 0; p < 4; ++p) {
        int kr = p * 16 + (threadIdx.x >> 4);
        int c4 = (threadIdx.x & 15) * 4;
        float4 v = *(const float4*)&W[(long)(k0 + kr) * DOUT + n0 + c4];
        t[c4 + 0][kr] = __float2bfloat16(v.x);
        t[c4 + 1][kr] = __float2bfloat16(v.y);
        t[c4 + 2][kr] = __float2bfloat16(v.z);
        t[c4 + 3][kr] = __float2bfloat16(v.w);
    }
    __syncthreads();
    bf16* O = Wt + (long)mat * DIN * DOUT;
#pragma unroll
    for (int i = 0; i < 2; ++i) {
        int l = threadIdx.x + i * 256;
        int n = l >> 3, c8 = (l & 7) * 8;
        pack8 o;
#pragma unroll
        for (int j = 0; j < 8; ++j) o.h[j] = t[n][c8 + j];
        *(bf16x8*)&O[(long)(n0 + n) * DIN + k0 + c8] = o.v;
    }
}

// ---------------- QKV projection: 8-wave pipelined core ----------------
// BM=128, BN=256, BK=64. 512 threads = 8 waves (2 M x 4 N), each wave a
// 64x64 sub-tile (acc[4][4] of 16x16x32 MFMA). Double-buffered LDS
// (A 16KB + B 32KB per buffer = 96 KiB), XOR-swizzled (T2).
// Deep pipeline: per phase {ds_read subtile | issue 3 global_load_lds ->
// barrier -> setprio(1) 16 MFMA setprio(0) -> barrier}; counted vmcnt(3)
// only at K-tile boundaries (T3+T4); loads stay in flight across barriers.
//
// Load sequence per K-tile: [B0a B0b B1a B1b Aa Ab] (2 per-wave loads per
// 16KB unit). Issue lead = 9 loads: kt.p0 issues kt+1{B1b,Aa,Ab},
// kt.p1 issues kt+2{B0a,B0b,B1a}. Clobber-safe: kt+2 units land in kt's
// buffer only after kt's reads of that unit completed (all B read in p0;
// A mi0..1 in p0, mi2..3 in p1), enforced by the phase entry barriers.

#define BAR() do { __builtin_amdgcn_sched_barrier(0); \
                   __builtin_amdgcn_s_barrier();      \
                   __builtin_amdgcn_sched_barrier(0); } while (0)

__global__ __launch_bounds__(512, 2)
void k_gemm_qkv(const bf16* __restrict__ xb, const bf16* __restrict__ Wt,
                bf16* __restrict__ QK, bf16* __restrict__ Vt)
{
    __shared__ __align__(16) bf16 smem[49152];     // 96 KiB
    bf16* sA = smem;                                // [2][8192]
    bf16* sB = smem + 16384;                        // [2][2][8192]

    const int tid = threadIdx.x;
    const int m0 = blockIdx.y * 128;
    const int n0 = blockIdx.x * 256;

    const bf16* Abase = xb + (long)m0 * DIN;
    const bf16* Bbase = Wt + (long)n0 * DIN;

    // staging: pass r covers rows r*64 + (tid>>3), pre-swizzled source col
    const int srow = tid >> 3;                      // 0..63
    const int scol = ((tid & 7) ^ (srow & 7)) * 8;

    const int lane = tid & 63, wave = tid >> 6;
    const int wr = wave >> 2, wc = wave & 3;        // 2 x 4 wave grid
    const int r = lane & 15, qd = lane >> 4;
    const int aRow  = (wr * 64 + r) * 64;           // + mi*1024
    const int bHalf = wc >> 1;
    const int bRow  = ((wc & 1) * 64 + r) * 64;     // + ni*1024
    const int slot0 = ( qd      ^ (r & 7)) * 8;     // ks=0
    const int slot1 = ((4 + qd) ^ (r & 7)) * 8;     // ks=1

    auto stageA = [&](int kt, int pass) {
        const bf16* src = Abase + (long)(srow + pass * 64) * DIN + kt * 64 + scol;
        gl16(src, &sA[(kt & 1) * 8192 + pass * 4096 + tid * 8]);
    };
    auto stageB = [&](int kt, int half, int pass) {
        const bf16* src = Bbase + (long)(half * 128 + srow + pass * 64) * DIN + kt * 64 + scol;
        gl16(src, &sB[(kt & 1) * 16384 + half * 8192 + pass * 4096 + tid * 8]);
    };

    f32x4 acc[4][4] = {};

    // prologue: kt0 complete + kt1 first 3 loads; keep 3 in flight
    stageB(0, 0, 0); stageB(0, 0, 1); stageB(0, 1, 0); stageB(0, 1, 1);
    stageA(0, 0);    stageA(0, 1);
    stageB(1, 0, 0); stageB(1, 0, 1); stageB(1, 1, 0);
    asm volatile("s_waitcnt vmcnt(3)" ::: "memory");
    BAR();

#pragma unroll 2
    for (int kt = 0; kt < 16; ++kt) {
        const int c = kt & 1;
        const bf16* A = sA + c * 8192;
        const bf16* B = sB + c * 16384 + bHalf * 8192;

        // ---- phase 0: read all B + A mi0..1; issue kt+1 {B1b, Aa, Ab}
        bf16x8 bv[4][2], af[2][2];
#pragma unroll
        for (int ni = 0; ni < 4; ++ni) {
            bv[ni][0] = *(const bf16x8*)&B[bRow + ni * 1024 + slot0];
            bv[ni][1] = *(const bf16x8*)&B[bRow + ni * 1024 + slot1];
        }
#pragma unroll
        for (int mi = 0; mi < 2; ++mi) {
            af[mi][0] = *(const bf16x8*)&A[aRow + mi * 1024 + slot0];
            af[mi][1] = *(const bf16x8*)&A[aRow + mi * 1024 + slot1];
        }
        if (kt + 1 < 16) { stageB(kt + 1, 1, 1); stageA(kt + 1, 0); stageA(kt + 1, 1); }
        BAR();
        asm volatile("s_waitcnt lgkmcnt(0)" ::: "memory");
        __builtin_amdgcn_s_setprio(1);
#pragma unroll
        for (int mi = 0; mi < 2; ++mi)
#pragma unroll
            for (int ni = 0; ni < 4; ++ni) {
                acc[mi][ni] = MFMA(af[mi][0], bv[ni][0], acc[mi][ni]);
                acc[mi][ni] = MFMA(af[mi][1], bv[ni][1], acc[mi][ni]);
            }
        __builtin_amdgcn_s_setprio(0);
        BAR();

        // ---- phase 1: read A mi2..3; issue kt+2 {B0a, B0b, B1a}
        bf16x8 ag[2][2];
#pragma unroll
        for (int mi = 0; mi < 2; ++mi) {
            ag[mi][0] = *(const bf16x8*)&A[aRow + (mi + 2) * 1024 + slot0];
            ag[mi][1] = *(const bf16x8*)&A[aRow + (mi + 2) * 1024 + slot1];
        }
        if (kt + 2 < 16) { stageB(kt + 2, 0, 0); stageB(kt + 2, 0, 1); stageB(kt + 2, 1, 0); }
        BAR();
        asm volatile("s_waitcnt lgkmcnt(0)" ::: "memory");
        __builtin_amdgcn_s_setprio(1);
#pragma unroll
        for (int mi = 0; mi < 2; ++mi)
#pragma unroll
            for (int ni = 0; ni < 4; ++ni) {
                acc[mi + 2][ni] = MFMA(ag[mi][0], bv[ni][0], acc[mi + 2][ni]);
                acc[mi + 2][ni] = MFMA(ag[mi][1], bv[ni][1], acc[mi + 2][ni]);
            }
        __builtin_amdgcn_s_setprio(0);
        // K-tile boundary: counted drain (next tile landed, 3 in flight)
        if (kt < 14)       { asm volatile("s_waitcnt vmcnt(3)" ::: "memory"); }
        else if (kt == 14) { asm volatile("s_waitcnt vmcnt(0)" ::: "memory"); }
        BAR();
    }

    // ---- epilogue ----
    const int bx = blockIdx.x;
    if (bx < 8) {                                   // Q|K: direct store
#pragma unroll
        for (int mi = 0; mi < 4; ++mi)
#pragma unroll
            for (int ni = 0; ni < 4; ++ni)
#pragma unroll
                for (int j = 0; j < 4; ++j) {
                    int row = m0 + wr * 64 + mi * 16 + qd * 4 + j;
                    int col = n0 + wc * 64 + ni * 16 + r;
                    QK[(long)row * 2048 + col] = __float2bfloat16(acc[mi][ni][j]);
                }
    } else {                                        // V: transpose via LDS
        const int ld = 136;                         // padded, 16B-aligned
        bf16* T = smem;                             // 256*136 <= 49152 elems
#pragma unroll
        for (int mi = 0; mi < 4; ++mi)
#pragma unroll
            for (int ni = 0; ni < 4; ++ni) {
                pack4 p;
#pragma unroll
                for (int j = 0; j < 4; ++j) p.h[j] = __float2bfloat16(acc[mi][ni][j]);
                int d_l = wc * 64 + ni * 16 + r;    // 0..255
                int s_l = wr * 64 + mi * 16 + qd * 4;
                *(uint2*)&T[d_l * ld + s_l] = p.u2;
            }
        __syncthreads();
        const int n0v = n0 - 2048;
        const int bb = m0 >> 11;
        const int s0 = m0 & 2047;
        bf16* Ob = Vt + (long)bb * DOUT * SEQ + s0;
#pragma unroll
        for (int p = 0; p < 8; ++p) {
            int l = tid + p * 512;                  // 0..4095
            int d = l >> 4, s8 = (l & 15) * 8;
            bf16x8 vv = *(const bf16x8*)&T[d * ld + s8];
            *(bf16x8*)&Ob[(long)(n0v + d) * SEQ + s8] = vv;
        }
    }
}

// ---------------- shared GEMM core (old, for scores/pv), BK=64 ----------------

__device__ __forceinline__ void gemm_core(
    const bf16* __restrict__ Ab, long lda,
    const bf16* __restrict__ Bb, long ldb,
    int nk, bf16* __restrict__ As, bf16* __restrict__ Bs,
    f32x4 acc[4][4])
{
    const int tid  = threadIdx.x;
    const int lane = tid & 63;
    const int wave = tid >> 6;
    const int wm = (wave >> 1) * 64;
    const int wn = (wave & 1) * 64;
    const int r  = lane & 15;
    const int qd = lane >> 4;

    const int row0 = tid >> 3;                    // 0..31
    const int c    = (tid & 7) ^ (row0 & 7);      // swizzled source chunk
    const long aoff = (long)row0 * lda + c * 8;
    const long boff = (long)row0 * ldb + c * 8;
    const long astep = 32 * lda, bstep = 32 * ldb;
    bf16* dA = &As[tid * 8];
    bf16* dB = &Bs[tid * 8];

    for (int kk = 0; kk < nk; ++kk) {
        const bf16* A = Ab + kk * 64 + aoff;
        const bf16* B = Bb + kk * 64 + boff;
#pragma unroll
        for (int i = 0; i < 4; ++i) {
            gl16(A + i * astep, dA + i * 2048);
            gl16(B + i * bstep, dB + i * 2048);
        }
        __syncthreads();                           // drains vmcnt
#pragma unroll
        for (int ks = 0; ks < 2; ++ks) {
            const int slot = ((ks * 4 + qd) ^ (r & 7)) * 8;
            bf16x8 af[4], bv[4];
#pragma unroll
            for (int mi = 0; mi < 4; ++mi)
                af[mi] = *(const bf16x8*)&As[(wm + mi * 16 + r) * 64 + slot];
#pragma unroll
            for (int ni = 0; ni < 4; ++ni)
                bv[ni] = *(const bf16x8*)&Bs[(wn + ni * 16 + r) * 64 + slot];
#pragma unroll
            for (int mi = 0; mi < 4; ++mi)
#pragma unroll
                for (int ni = 0; ni < 4; ++ni)
                    acc[mi][ni] = MFMA(af[mi], bv[ni], acc[mi][ni]);
        }
        __syncthreads();
    }
}

// ---------------- scores + exp + row-sum (unchanged) ----------------

__global__ __launch_bounds__(256, 3)
void k_gemm_scores(const bf16* __restrict__ QK, bf16* __restrict__ P,
                   float* __restrict__ rowSum)
{
    const int b = blockIdx.z, qt = blockIdx.y, kt = blockIdx.x;
    if (kt > qt) return;
    __shared__ __align__(16) bf16 As[128 * 64];
    __shared__ __align__(16) bf16 Bs[128 * 64];
    const bf16* A  = QK + (long)b * SEQ * 2048;
    const bf16* Bt = A + 1024;
    f32x4 acc[4][4] = {};
    gemm_core(A + (long)qt * 128 * 2048, 2048, Bt + (long)kt * 128 * 2048, 2048,
              DIN / 64, As, Bs, acc);

    bf16* Pb = P + (long)b * SEQ * SEQ;
    float* RS = rowSum + b * SEQ;
    const int lane = threadIdx.x & 63, wave = threadIdx.x >> 6;
    const int wm = (wave >> 1) * 64, wn = (wave & 1) * 64;
    const int r = lane & 15, qd = lane >> 4;

    float rp[4][4];
#pragma unroll
    for (int mi = 0; mi < 4; ++mi)
#pragma unroll
        for (int j = 0; j < 4; ++j) rp[mi][j] = 0.f;

#pragma unroll
    for (int mi = 0; mi < 4; ++mi)
#pragma unroll
        for (int ni = 0; ni < 4; ++ni)
#pragma unroll
            for (int j = 0; j < 4; ++j) {
                int row = qt * 128 + wm + mi * 16 + qd * 4 + j;
                int col = kt * 128 + wn + ni * 16 + r;
                float e = (col > row) ? 0.f : __expf(acc[mi][ni][j] * 0.03125f);
                rp[mi][j] += e;
                Pb[(long)row * SEQ + col] = __float2bfloat16(e);
            }
#pragma unroll
    for (int d = 1; d < 16; d <<= 1)
#pragma unroll
        for (int mi = 0; mi < 4; ++mi)
#pragma unroll
            for (int j = 0; j < 4; ++j)
                rp[mi][j] += __shfl_xor(rp[mi][j], d, 64);
    if (r == 0) {
#pragma unroll
        for (int mi = 0; mi < 4; ++mi)
#pragma unroll
            for (int j = 0; j < 4; ++j) {
                int row = qt * 128 + wm + mi * 16 + qd * 4 + j;
                atomicAdd(&RS[row], rp[mi][j]);
            }
    }
}

// ---------------- PV: O = (P @ V) / rowSum (unchanged) ----------------

__global__ __launch_bounds__(256, 3)
void k_gemm_pv(const bf16* __restrict__ P, const bf16* __restrict__ Vt,
               const float* __restrict__ rowSum, float* __restrict__ O)
{
    const int b = blockIdx.z, nt = blockIdx.x;
    const int qt = (SEQ / 128 - 1) - blockIdx.y;   // heavy (large nk) first
    __shared__ __align__(16) bf16 As[128 * 64];
    __shared__ __align__(16) bf16 Bs[128 * 64];
    const bf16* A  = P + (long)b * SEQ * SEQ + (long)qt * 128 * SEQ;
    const bf16* Bt = Vt + (long)b * DOUT * SEQ;
    const int nk = (qt + 1) * 2;                   // K up to (qt+1)*128, BK=64
    f32x4 acc[4][4] = {};
    gemm_core(A, SEQ, Bt + (long)nt * 128 * SEQ, SEQ, nk, As, Bs, acc);

    float* Ob = O + (long)b * SEQ * DOUT;
    const float* RS = rowSum + b * SEQ;
    const int lane = threadIdx.x & 63, wave = threadIdx.x >> 6;
    const int wm = (wave >> 1) * 64, wn = (wave & 1) * 64;
    const int r = lane & 15, qd = lane >> 4;
#pragma unroll
    for (int mi = 0; mi < 4; ++mi)
#pragma unroll
        for (int j = 0; j < 4; ++j) {
            int row = qt * 128 + wm + mi * 16 + qd * 4 + j;
            float inv = 1.0f / RS[row];
#pragma unroll
            for (int ni = 0; ni < 4; ++ni) {
                int col = nt * 128 + wn + ni * 16 + r;
                Ob[(long)row * DOUT + col] = acc[mi][ni][j] * inv;
            }
        }
}

// ---------------- launch ----------------

extern "C" void kernel_launch(void* const* d_in, const int* in_sizes, int n_in,
                              void* d_out, int out_size, void* d_ws, size_t ws_size,
                              hipStream_t stream)
{
    const float* x  = (const float*)d_in[0];
    const float* Wq = (const float*)d_in[1];
    const float* Wk = (const float*)d_in[2];
    const float* Wv = (const float*)d_in[3];
    float* out = (float*)d_out;

    char* ws = (char*)d_ws;
    bf16*  xb = (bf16*)(ws);                        // 16 MiB
    bf16*  Wt = (bf16*)(ws + 16777216);             //  6 MiB
    bf16*  QK = (bf16*)(ws + 23068672);             // 32 MiB  [row][2048] = Q|K
    bf16*  Vt = (bf16*)(ws + 56623104);             // 16 MiB  [b][d][s]
    bf16*  P  = (bf16*)(ws + 73400320);             // 32 MiB
    float* RS = (float*)(ws + 106954752);           // 32 KiB  (total ~102 MiB)

    hipMemsetAsync(RS, 0, BATCH * SEQ * sizeof(float), stream);
    k_prep<<<dim3(8192 + 768), 256, 0, stream>>>(x, Wq, Wk, Wv, xb, Wt);
    k_gemm_qkv<<<dim3(N3 / 256, MTOT / 128), 512, 0, stream>>>(xb, Wt, QK, Vt);
    k_gemm_scores<<<dim3(SEQ / 128, SEQ / 128, BATCH), 256, 0, stream>>>(QK, P, RS);
    k_gemm_pv<<<dim3(DOUT / 128, SEQ / 128, BATCH), 256, 0, stream>>>(P, Vt, RS, out);
}

// Round 2
// 221.736 us; speedup vs baseline: 1.0071x; 1.0033x over previous
//
#include <hip/hip_runtime.h>
#include <hip/hip_bf16.h>

#define BATCH 4
#define SEQ   2048
#define DIN   1024
#define DOUT  1024
#define N3    3072
#define MTOT  (BATCH*SEQ)

typedef __hip_bfloat16 bf16;
typedef __attribute__((ext_vector_type(8))) short bf16x8;
typedef __attribute__((ext_vector_type(4))) float f32x4;

#define MFMA(a,b,c) __builtin_amdgcn_mfma_f32_16x16x32_bf16(a,b,c,0,0,0)

union pack4 { bf16 h[4]; uint2 u2; };
union pack8 { bf16 h[8]; bf16x8 v; };

// async 16B global->LDS (DMA, no VGPR round-trip)
__device__ __forceinline__ void gl16(const bf16* g, bf16* l)
{
    __builtin_amdgcn_global_load_lds(
        (const __attribute__((address_space(1))) void*)g,
        (__attribute__((address_space(3))) void*)l, 16, 0, 0);
}

// ---------------- fused conversions (unchanged) ----------------

__global__ __launch_bounds__(256)
void k_prep(const float* __restrict__ x, const float* __restrict__ Wq,
            const float* __restrict__ Wk, const float* __restrict__ Wv,
            bf16* __restrict__ xb, bf16* __restrict__ Wt)
{
    __shared__ bf16 t[64][68];
    const int bid = blockIdx.x;
    if (bid < 8192) {
        long i = ((long)bid * 256 + threadIdx.x) * 4;
        float4 v = *(const float4*)(x + i);
        pack4 o;
        o.h[0] = __float2bfloat16(v.x);
        o.h[1] = __float2bfloat16(v.y);
        o.h[2] = __float2bfloat16(v.z);
        o.h[3] = __float2bfloat16(v.w);
        *(uint2*)(xb + i) = o.u2;
        return;
    }
    const int idx = bid - 8192;                // 0..767
    const int mat = idx >> 8;
    const int rem = idx & 255;
    const int k0 = (rem >> 4) * 64, n0 = (rem & 15) * 64;
    const float* W = (mat == 0) ? Wq : ((mat == 1) ? Wk : Wv);
#pragma unroll
    for (int p = 0; p < 4; ++p) {
        int kr = p * 16 + (threadIdx.x >> 4);
        int c4 = (threadIdx.x & 15) * 4;
        float4 v = *(const float4*)&W[(long)(k0 + kr) * DOUT + n0 + c4];
        t[c4 + 0][kr] = __float2bfloat16(v.x);
        t[c4 + 1][kr] = __float2bfloat16(v.y);
        t[c4 + 2][kr] = __float2bfloat16(v.z);
        t[c4 + 3][kr] = __float2bfloat16(v.w);
    }
    __syncthreads();
    bf16* O = Wt + (long)mat * DIN * DOUT;
#pragma unroll
    for (int i = 0; i < 2; ++i) {
        int l = threadIdx.x + i * 256;
        int n = l >> 3, c8 = (l & 7) * 8;
        pack8 o;
#pragma unroll
        for (int j = 0; j < 8; ++j) o.h[j] = t[n][c8 + j];
        *(bf16x8*)&O[(long)(n0 + n) * DIN + k0 + c8] = o.v;
    }
}

// ---------------- QKV projection: register-pipelined core ----------------
// BM=128, BN=256, BK=64. 512 threads = 8 waves (2M x 4N), per-wave 64x64.
// Double-buffered LDS (96 KiB), XOR-swizzled. ONE barrier per K-tile.
// Inside a K-tile: 4 reg-pipelined phases with COUNTED lgkmcnt — phase p's
// MFMAs overlap phase p+1's ds_reads (per-wave ILP + cross-wave TLP, no
// intra-tile barriers so SIMD wave pairs drift and cover each other).
// Staging for kt+1 issues at kt start (full-tile lookahead, ~2000 cyc to
// land) so the vmcnt(0) before the tile-end barrier is effectively free.

#define WAITLG(n) do { asm volatile("s_waitcnt lgkmcnt(" #n ")" ::: "memory"); \
                       __builtin_amdgcn_sched_barrier(0); } while (0)

__global__ __launch_bounds__(512, 2)
void k_gemm_qkv(const bf16* __restrict__ xb, const bf16* __restrict__ Wt,
                bf16* __restrict__ QK, bf16* __restrict__ Vt)
{
    __shared__ __align__(16) bf16 smem[49152];     // 96 KiB
    bf16* sA = smem;                                // [2][8192]
    bf16* sB = smem + 16384;                        // [2][2][8192]

    const int tid = threadIdx.x;

    // bijective XCD swizzle: 768 blocks = 8 XCDs x 96 contiguous tiles.
    // XCD k owns m-rows 8k..8k+7 (all 12 n-tiles) -> A-panel L2 reuse.
    const int wg  = blockIdx.y * 12 + blockIdx.x;   // hw dispatch index
    const int swz = (wg & 7) * 96 + (wg >> 3);
    const int bx  = swz % 12, by = swz / 12;
    const int m0 = by * 128;
    const int n0 = bx * 256;

    const bf16* Abase = xb + (long)m0 * DIN;
    const bf16* Bbase = Wt + (long)n0 * DIN;

    // staging: pass r covers rows r*64 + (tid>>3), pre-swizzled source col
    const int srow = tid >> 3;                      // 0..63
    const int scol = ((tid & 7) ^ (srow & 7)) * 8;

    const int lane = tid & 63, wave = tid >> 6;
    const int wr = wave >> 2, wc = wave & 3;        // 2 x 4 wave grid
    const int r = lane & 15, qd = lane >> 4;
    const int aRow  = (wr * 64 + r) * 64;           // + mi*1024
    const int bHalf = wc >> 1;
    const int bRow  = ((wc & 1) * 64 + r) * 64;     // + ni*1024
    const int slot0 = ( qd      ^ (r & 7)) * 8;     // ks=0
    const int slot1 = ((4 + qd) ^ (r & 7)) * 8;     // ks=1

    auto stageA = [&](int kt, int pass) {
        const bf16* src = Abase + (long)(srow + pass * 64) * DIN + kt * 64 + scol;
        gl16(src, &sA[(kt & 1) * 8192 + pass * 4096 + tid * 8]);
    };
    auto stageB = [&](int kt, int half, int pass) {
        const bf16* src = Bbase + (long)(half * 128 + srow + pass * 64) * DIN + kt * 64 + scol;
        gl16(src, &sB[(kt & 1) * 16384 + half * 8192 + pass * 4096 + tid * 8]);
    };

    f32x4 acc[4][4] = {};

    // prologue: tile 0 staged + drained
    stageB(0, 0, 0); stageB(0, 0, 1); stageB(0, 1, 0); stageB(0, 1, 1);
    stageA(0, 0);    stageA(0, 1);
    asm volatile("s_waitcnt vmcnt(0)" ::: "memory");
    __builtin_amdgcn_sched_barrier(0);
    __builtin_amdgcn_s_barrier();
    __builtin_amdgcn_sched_barrier(0);

#pragma unroll 2
    for (int kt = 0; kt < 16; ++kt) {
        const int c = kt & 1;
        const bf16* A = sA + c * 8192;
        const bf16* B = sB + c * 16384 + bHalf * 8192;

        // stage next tile into other buffer; lands during this tile
        if (kt + 1 < 16) {
            stageB(kt + 1, 0, 0); stageB(kt + 1, 0, 1);
            stageB(kt + 1, 1, 0); stageB(kt + 1, 1, 1);
            stageA(kt + 1, 0);    stageA(kt + 1, 1);
        }

        bf16x8 a0[2], a1[2], a2[2], a3[2], b0[4], b1[4];

        // p0 reads (6): A m0,m1 ks0 + B ks0
        a0[0] = *(const bf16x8*)&A[aRow + 0 * 1024 + slot0];
        a0[1] = *(const bf16x8*)&A[aRow + 1 * 1024 + slot0];
#pragma unroll
        for (int ni = 0; ni < 4; ++ni)
            b0[ni] = *(const bf16x8*)&B[bRow + ni * 1024 + slot0];
        // p1 reads (2): A m2,m3 ks0
        a1[0] = *(const bf16x8*)&A[aRow + 2 * 1024 + slot0];
        a1[1] = *(const bf16x8*)&A[aRow + 3 * 1024 + slot0];
        WAITLG(2);                                  // p0 ready
        __builtin_amdgcn_s_setprio(1);
#pragma unroll
        for (int ni = 0; ni < 4; ++ni) {
            acc[0][ni] = MFMA(a0[0], b0[ni], acc[0][ni]);
            acc[1][ni] = MFMA(a0[1], b0[ni], acc[1][ni]);
        }
        __builtin_amdgcn_s_setprio(0);

        // p2 reads (6): A m0,m1 ks1 + B ks1
        a2[0] = *(const bf16x8*)&A[aRow + 0 * 1024 + slot1];
        a2[1] = *(const bf16x8*)&A[aRow + 1 * 1024 + slot1];
#pragma unroll
        for (int ni = 0; ni < 4; ++ni)
            b1[ni] = *(const bf16x8*)&B[bRow + ni * 1024 + slot1];
        WAITLG(6);                                  // p1 ready (a1)
        __builtin_amdgcn_s_setprio(1);
#pragma unroll
        for (int ni = 0; ni < 4; ++ni) {
            acc[2][ni] = MFMA(a1[0], b0[ni], acc[2][ni]);
            acc[3][ni] = MFMA(a1[1], b0[ni], acc[3][ni]);
        }
        __builtin_amdgcn_s_setprio(0);

        // p3 reads (2): A m2,m3 ks1
        a3[0] = *(const bf16x8*)&A[aRow + 2 * 1024 + slot1];
        a3[1] = *(const bf16x8*)&A[aRow + 3 * 1024 + slot1];
        WAITLG(2);                                  // p2 ready
        __builtin_amdgcn_s_setprio(1);
#pragma unroll
        for (int ni = 0; ni < 4; ++ni) {
            acc[0][ni] = MFMA(a2[0], b1[ni], acc[0][ni]);
            acc[1][ni] = MFMA(a2[1], b1[ni], acc[1][ni]);
        }
        __builtin_amdgcn_s_setprio(0);

        WAITLG(0);                                  // p3 ready
        __builtin_amdgcn_s_setprio(1);
#pragma unroll
        for (int ni = 0; ni < 4; ++ni) {
            acc[2][ni] = MFMA(a3[0], b1[ni], acc[2][ni]);
            acc[3][ni] = MFMA(a3[1], b1[ni], acc[3][ni]);
        }
        __builtin_amdgcn_s_setprio(0);

        // tile end: staging drained (issued a whole tile ago), barrier
        asm volatile("s_waitcnt vmcnt(0)" ::: "memory");
        __builtin_amdgcn_sched_barrier(0);
        __builtin_amdgcn_s_barrier();
        __builtin_amdgcn_sched_barrier(0);
    }

    // ---- epilogue ----
    if (bx < 8) {                                   // Q|K: direct store
#pragma unroll
        for (int mi = 0; mi < 4; ++mi)
#pragma unroll
            for (int ni = 0; ni < 4; ++ni)
#pragma unroll
                for (int j = 0; j < 4; ++j) {
                    int row = m0 + wr * 64 + mi * 16 + qd * 4 + j;
                    int col = n0 + wc * 64 + ni * 16 + r;
                    QK[(long)row * 2048 + col] = __float2bfloat16(acc[mi][ni][j]);
                }
    } else {                                        // V: transpose via LDS
        const int ld = 136;                         // padded, 16B-aligned
        bf16* T = smem;                             // 256*136 <= 49152 elems
#pragma unroll
        for (int mi = 0; mi < 4; ++mi)
#pragma unroll
            for (int ni = 0; ni < 4; ++ni) {
                pack4 p;
#pragma unroll
                for (int j = 0; j < 4; ++j) p.h[j] = __float2bfloat16(acc[mi][ni][j]);
                int d_l = wc * 64 + ni * 16 + r;    // 0..255
                int s_l = wr * 64 + mi * 16 + qd * 4;
                *(uint2*)&T[d_l * ld + s_l] = p.u2;
            }
        __syncthreads();
        const int n0v = n0 - 2048;
        const int bb = m0 >> 11;
        const int s0 = m0 & 2047;
        bf16* Ob = Vt + (long)bb * DOUT * SEQ + s0;
#pragma unroll
        for (int p = 0; p < 8; ++p) {
            int l = tid + p * 512;                  // 0..4095
            int d = l >> 4, s8 = (l & 15) * 8;
            bf16x8 vv = *(const bf16x8*)&T[d * ld + s8];
            *(bf16x8*)&Ob[(long)(n0v + d) * SEQ + s8] = vv;
        }
    }
}

// ---------------- shared GEMM core (scores/pv), BK=64 ----------------

__device__ __forceinline__ void gemm_core(
    const bf16* __restrict__ Ab, long lda,
    const bf16* __restrict__ Bb, long ldb,
    int nk, bf16* __restrict__ As, bf16* __restrict__ Bs,
    f32x4 acc[4][4])
{
    const int tid  = threadIdx.x;
    const int lane = tid & 63;
    const int wave = tid >> 6;
    const int wm = (wave >> 1) * 64;
    const int wn = (wave & 1) * 64;
    const int r  = lane & 15;
    const int qd = lane >> 4;

    const int row0 = tid >> 3;                    // 0..31
    const int c    = (tid & 7) ^ (row0 & 7);      // swizzled source chunk
    const long aoff = (long)row0 * lda + c * 8;
    const long boff = (long)row0 * ldb + c * 8;
    const long astep = 32 * lda, bstep = 32 * ldb;
    bf16* dA = &As[tid * 8];
    bf16* dB = &Bs[tid * 8];

    for (int kk = 0; kk < nk; ++kk) {
        const bf16* A = Ab + kk * 64 + aoff;
        const bf16* B = Bb + kk * 64 + boff;
#pragma unroll
        for (int i = 0; i < 4; ++i) {
            gl16(A + i * astep, dA + i * 2048);
            gl16(B + i * bstep, dB + i * 2048);
        }
        __syncthreads();                           // drains vmcnt
#pragma unroll
        for (int ks = 0; ks < 2; ++ks) {
            const int slot = ((ks * 4 + qd) ^ (r & 7)) * 8;
            bf16x8 af[4], bv[4];
#pragma unroll
            for (int mi = 0; mi < 4; ++mi)
                af[mi] = *(const bf16x8*)&As[(wm + mi * 16 + r) * 64 + slot];
#pragma unroll
            for (int ni = 0; ni < 4; ++ni)
                bv[ni] = *(const bf16x8*)&Bs[(wn + ni * 16 + r) * 64 + slot];
#pragma unroll
            for (int mi = 0; mi < 4; ++mi)
#pragma unroll
                for (int ni = 0; ni < 4; ++ni)
                    acc[mi][ni] = MFMA(af[mi], bv[ni], acc[mi][ni]);
        }
        __syncthreads();
    }
}

// ---------------- scores + exp + row-sum (unchanged) ----------------

__global__ __launch_bounds__(256, 3)
void k_gemm_scores(const bf16* __restrict__ QK, bf16* __restrict__ P,
                   float* __restrict__ rowSum)
{
    const int b = blockIdx.z, qt = blockIdx.y, kt = blockIdx.x;
    if (kt > qt) return;
    __shared__ __align__(16) bf16 As[128 * 64];
    __shared__ __align__(16) bf16 Bs[128 * 64];
    const bf16* A  = QK + (long)b * SEQ * 2048;
    const bf16* Bt = A + 1024;
    f32x4 acc[4][4] = {};
    gemm_core(A + (long)qt * 128 * 2048, 2048, Bt + (long)kt * 128 * 2048, 2048,
              DIN / 64, As, Bs, acc);

    bf16* Pb = P + (long)b * SEQ * SEQ;
    float* RS = rowSum + b * SEQ;
    const int lane = threadIdx.x & 63, wave = threadIdx.x >> 6;
    const int wm = (wave >> 1) * 64, wn = (wave & 1) * 64;
    const int r = lane & 15, qd = lane >> 4;

    float rp[4][4];
#pragma unroll
    for (int mi = 0; mi < 4; ++mi)
#pragma unroll
        for (int j = 0; j < 4; ++j) rp[mi][j] = 0.f;

#pragma unroll
    for (int mi = 0; mi < 4; ++mi)
#pragma unroll
        for (int ni = 0; ni < 4; ++ni)
#pragma unroll
            for (int j = 0; j < 4; ++j) {
                int row = qt * 128 + wm + mi * 16 + qd * 4 + j;
                int col = kt * 128 + wn + ni * 16 + r;
                float e = (col > row) ? 0.f : __expf(acc[mi][ni][j] * 0.03125f);
                rp[mi][j] += e;
                Pb[(long)row * SEQ + col] = __float2bfloat16(e);
            }
#pragma unroll
    for (int d = 1; d < 16; d <<= 1)
#pragma unroll
        for (int mi = 0; mi < 4; ++mi)
#pragma unroll
            for (int j = 0; j < 4; ++j)
                rp[mi][j] += __shfl_xor(rp[mi][j], d, 64);
    if (r == 0) {
#pragma unroll
        for (int mi = 0; mi < 4; ++mi)
#pragma unroll
            for (int j = 0; j < 4; ++j) {
                int row = qt * 128 + wm + mi * 16 + qd * 4 + j;
                atomicAdd(&RS[row], rp[mi][j]);
            }
    }
}

// ---------------- PV: O = (P @ V) / rowSum (unchanged) ----------------

__global__ __launch_bounds__(256, 3)
void k_gemm_pv(const bf16* __restrict__ P, const bf16* __restrict__ Vt,
               const float* __restrict__ rowSum, float* __restrict__ O)
{
    const int b = blockIdx.z, nt = blockIdx.x;
    const int qt = (SEQ / 128 - 1) - blockIdx.y;   // heavy (large nk) first
    __shared__ __align__(16) bf16 As[128 * 64];
    __shared__ __align__(16) bf16 Bs[128 * 64];
    const bf16* A  = P + (long)b * SEQ * SEQ + (long)qt * 128 * SEQ;
    const bf16* Bt = Vt + (long)b * DOUT * SEQ;
    const int nk = (qt + 1) * 2;                   // K up to (qt+1)*128, BK=64
    f32x4 acc[4][4] = {};
    gemm_core(A, SEQ, Bt + (long)nt * 128 * SEQ, SEQ, nk, As, Bs, acc);

    float* Ob = O + (long)b * SEQ * DOUT;
    const float* RS = rowSum + b * SEQ;
    const int lane = threadIdx.x & 63, wave = threadIdx.x >> 6;
    const int wm = (wave >> 1) * 64, wn = (wave & 1) * 64;
    const int r = lane & 15, qd = lane >> 4;
#pragma unroll
    for (int mi = 0; mi < 4; ++mi)
#pragma unroll
        for (int j = 0; j < 4; ++j) {
            int row = qt * 128 + wm + mi * 16 + qd * 4 + j;
            float inv = 1.0f / RS[row];
#pragma unroll
            for (int ni = 0; ni < 4; ++ni) {
                int col = nt * 128 + wn + ni * 16 + r;
                Ob[(long)row * DOUT + col] = acc[mi][ni][j] * inv;
            }
        }
}

// ---------------- launch ----------------

extern "C" void kernel_launch(void* const* d_in, const int* in_sizes, int n_in,
                              void* d_out, int out_size, void* d_ws, size_t ws_size,
                              hipStream_t stream)
{
    const float* x  = (const float*)d_in[0];
    const float* Wq = (const float*)d_in[1];
    const float* Wk = (const float*)d_in[2];
    const float* Wv = (const float*)d_in[3];
    float* out = (float*)d_out;

    char* ws = (char*)d_ws;
    bf16*  xb = (bf16*)(ws);                        // 16 MiB
    bf16*  Wt = (bf16*)(ws + 16777216);             //  6 MiB
    bf16*  QK = (bf16*)(ws + 23068672);             // 32 MiB  [row][2048] = Q|K
    bf16*  Vt = (bf16*)(ws + 56623104);             // 16 MiB  [b][d][s]
    bf16*  P  = (bf16*)(ws + 73400320);             // 32 MiB
    float* RS = (float*)(ws + 106954752);           // 32 KiB  (total ~102 MiB)

    hipMemsetAsync(RS, 0, BATCH * SEQ * sizeof(float), stream);
    k_prep<<<dim3(8192 + 768), 256, 0, stream>>>(x, Wq, Wk, Wv, xb, Wt);
    k_gemm_qkv<<<dim3(N3 / 256, MTOT / 128), 512, 0, stream>>>(xb, Wt, QK, Vt);
    k_gemm_scores<<<dim3(SEQ / 128, SEQ / 128, BATCH), 256, 0, stream>>>(QK, P, RS);
    k_gemm_pv<<<dim3(DOUT / 128, SEQ / 128, BATCH), 256, 0, stream>>>(P, Vt, RS, out);
}